// Round 3
// baseline (417.239 us; speedup 1.0000x reference)
//
#include <hip/hip_runtime.h>
#include <stdint.h>

// ============================================================================
// ConcreteSelect: Y[b,s] = X[b, argmax_d(logits[s,d] + gumbel(key=42)[s,d])]
// Gumbel-softmax hard=True forward == one-hot column gather of X.
// PRNG: JAX threefry2x32, partitionable mode: x=(hi32(i),lo32(i)), bits=y0^y1.
// Bit-exact (absmax 0.0 in rounds 1-2).
//
// R3: gather MLP doubled — 16 scattered loads issued back-to-back per thread
// (vmcnt covers all 16 before first store), nontemporal Y stores to avoid
// evicting shared X lines from L2. Argmax unchanged from R2 (float fast path
// + double re-verify of near-max candidates).
// ============================================================================

#define S_ROWS 256
#define D_COLS 10000
#define B_ROWS 8192

__device__ __forceinline__ void threefry2x32(uint32_t& x0, uint32_t& x1) {
  const uint32_t k0 = 0u;
  const uint32_t k1 = 42u;
  const uint32_t k2 = 0x1BD11BDAu ^ k0 ^ k1;
  x0 += k0; x1 += k1;
#define TFR(r) { x0 += x1; x1 = (x1 << (r)) | (x1 >> (32 - (r))); x1 ^= x0; }
  TFR(13) TFR(15) TFR(26) TFR(6)   x0 += k1; x1 += k2 + 1u;
  TFR(17) TFR(29) TFR(16) TFR(24)  x0 += k2; x1 += k0 + 2u;
  TFR(13) TFR(15) TFR(26) TFR(6)   x0 += k0; x1 += k1 + 3u;
  TFR(17) TFR(29) TFR(16) TFR(24)  x0 += k1; x1 += k2 + 4u;
  TFR(13) TFR(15) TFR(26) TFR(6)   x0 += k2; x1 += k0 + 5u;
#undef TFR
}

__device__ __forceinline__ uint32_t jax_random_bits(uint32_t i) {
  uint32_t x0 = 0u, x1 = i;
  threefry2x32(x0, x1);
  return x0 ^ x1;
}

__device__ __forceinline__ float uniform_from_bits(uint32_t bits) {
  uint32_t fb = (bits >> 9) | 0x3f800000u;     // [1,2)
  float u = __uint_as_float(fb) - 1.0f;        // [0,1)
  if (u <= 0.0f) u = 1.17549435e-38f;          // max(tiny, u)
  return u;
}

__device__ __forceinline__ float gumbel_f(uint32_t bits) {
  float u  = uniform_from_bits(bits);
  float nl = -logf(u);
  return -logf(nl);
}

__device__ __forceinline__ double gumbel_d(uint32_t bits) {
  float u = uniform_from_bits(bits);
  double lu = log((double)u);
  return -log(-lu);
}

#define ARGMAX_THREADS 1024
#define CAND_MAX 64

__global__ __launch_bounds__(ARGMAX_THREADS)
void argmax_gumbel_kernel(const float* __restrict__ logits, int* __restrict__ idx_out) {
  const int s   = blockIdx.x;      // 0..255
  const int tid = threadIdx.x;     // 0..1023
  const int base = s * D_COLS;

  __shared__ float zbuf[D_COLS];                 // 40 KB
  __shared__ float sv[ARGMAX_THREADS];           // 4 KB
  __shared__ int   si[ARGMAX_THREADS];           // 4 KB
  __shared__ int   n_cand;
  __shared__ int   cand[CAND_MAX];

  if (tid == 0) n_cand = 0;

  float best = -1.0e30f;
  int   bi   = 0;
  for (int d = tid; d < D_COLS; d += ARGMAX_THREADS) {
    uint32_t bits = jax_random_bits((uint32_t)(base + d));
    float z = logits[base + d] + gumbel_f(bits);
    zbuf[d] = z;
    if (z > best) { best = z; bi = d; }
  }
  sv[tid] = best; si[tid] = bi;
  __syncthreads();
  for (int off = ARGMAX_THREADS / 2; off > 0; off >>= 1) {
    if (tid < off) {
      float ov = sv[tid + off]; int oi = si[tid + off];
      if (ov > sv[tid] || (ov == sv[tid] && oi < si[tid])) { sv[tid] = ov; si[tid] = oi; }
    }
    __syncthreads();
  }

  // Double precision decides among all columns within EPS of the float max.
  const float thresh = sv[0] - 1.0e-3f;
  for (int d = tid; d < D_COLS; d += ARGMAX_THREADS) {
    if (zbuf[d] >= thresh) {
      int pos = atomicAdd(&n_cand, 1);
      if (pos < CAND_MAX) cand[pos] = d;
    }
  }
  __syncthreads();

  if (tid == 0) {
    int    nc   = n_cand < CAND_MAX ? n_cand : CAND_MAX;
    double bz   = -1.0e300;
    int    bidx = 0x7fffffff;
    for (int i = 0; i < nc; ++i) {
      int d = cand[i];
      double z = (double)logits[base + d] + gumbel_d(jax_random_bits((uint32_t)(base + d)));
      if (z > bz || (z == bz && d < bidx)) { bz = z; bidx = d; }
    }
    idx_out[s] = bidx;
  }
}

// 16 scattered loads in flight per thread before any store; nontemporal
// stores keep Y from displacing X lines in L2 (same-line column reuse
// across waves depends on L2 hits).
#define ROWS_PER_BLOCK 16
__global__ __launch_bounds__(256)
void gather_cols_kernel(const float* __restrict__ X,
                        const int* __restrict__ idx,
                        float* __restrict__ Y) {
  const int s   = threadIdx.x;           // output column 0..255
  const int col = idx[s];                // 1 KB broadcast, L2-hot
  const long b0 = (long)blockIdx.x * ROWS_PER_BLOCK;
  const float* xp = X + b0 * D_COLS + col;
  float v[ROWS_PER_BLOCK];
#pragma unroll
  for (int r = 0; r < ROWS_PER_BLOCK; ++r)
    v[r] = xp[(long)r * D_COLS];         // 16 independent scattered loads
  float* yp = Y + b0 * S_ROWS + s;
#pragma unroll
  for (int r = 0; r < ROWS_PER_BLOCK; ++r)
    __builtin_nontemporal_store(v[r], yp + (long)r * S_ROWS);  // coalesced
}

extern "C" void kernel_launch(void* const* d_in, const int* in_sizes, int n_in,
                              void* d_out, int out_size, void* d_ws, size_t ws_size,
                              hipStream_t stream) {
  const float* X      = (const float*)d_in[0];   // [8192, 10000] fp32
  const float* logits = (const float*)d_in[1];   // [256, 10000] fp32
  float*       Y      = (float*)d_out;           // [8192, 256] fp32
  int*         idx    = (int*)d_ws;              // 256 ints scratch

  argmax_gumbel_kernel<<<S_ROWS, ARGMAX_THREADS, 0, stream>>>(logits, idx);
  gather_cols_kernel<<<B_ROWS / ROWS_PER_BLOCK, 256, 0, stream>>>(X, idx, Y);
}